// Round 3
// baseline (257.061 us; speedup 1.0000x reference)
//
#include <hip/hip_runtime.h>
#include <hip/hip_bf16.h>
#include <stdint.h>

#define NTOK 196
#define NB   64
#define CCH  512
#define HID  2048
#define MTOT (NB * NTOK)   // 12544

typedef __attribute__((ext_vector_type(8))) short  short8v;
typedef __attribute__((ext_vector_type(4))) float  float4v;

// ---------------- helpers ----------------

__device__ __forceinline__ void mfma16x16(float4v& d, short8v a, short8v b) {
  asm("v_mfma_f32_16x16x32_bf16 %0, %1, %2, %0" : "+v"(d) : "v"(a), "v"(b));
}

__device__ __forceinline__ void gload_lds16(const void* gsrc, void* ldst) {
  __builtin_amdgcn_global_load_lds(
      (const __attribute__((address_space(1))) unsigned int*)gsrc,
      (__attribute__((address_space(3))) unsigned int*)ldst, 16, 0, 0);
}

__device__ __forceinline__ int swz4(int r) { return (r ^ (r >> 2)) & 3; }

// ---------------- prep: BN constants ----------------

__global__ void prep_consts(const float* __restrict__ bn_g, const float* __restrict__ bn_b,
                            const float* __restrict__ bn_m, const float* __restrict__ bn_v,
                            const float* __restrict__ fbn_g, const float* __restrict__ fbn_b,
                            const float* __restrict__ fbn_m, const float* __restrict__ fbn_v,
                            float* __restrict__ cst) {
  int c = blockIdx.x * blockDim.x + threadIdx.x;
  if (c < CCH) {
    float i1 = bn_g[c] * rsqrtf(bn_v[c] + 1e-5f);
    cst[c] = i1;
    cst[512 + c] = bn_b[c] - bn_m[c] * i1;
    float i2 = fbn_g[c] * rsqrtf(fbn_v[c] + 1e-5f);
    cst[1024 + c] = i2;
    cst[1536 + c] = fbn_b[c] - fbn_m[c] * i2;
  }
}

// ---------------- weights fp32 -> bf16 ----------------

__global__ void cvt_weights(const float* __restrict__ qkv_w, const float* __restrict__ proj_w,
                            const float* __restrict__ fc1_w, const float* __restrict__ fc2_w,
                            __hip_bfloat16* __restrict__ qkvb, __hip_bfloat16* __restrict__ projb,
                            __hip_bfloat16* __restrict__ fc1b, __hip_bfloat16* __restrict__ fc2b) {
  int i4 = blockIdx.x * blockDim.x + threadIdx.x;    // unit = 4 floats
  const int nq = 1536 * 512 / 4;
  const int np = 512 * 512 / 4;
  const int n1 = 2048 * 512 / 4;
  const float* src;
  __hip_bfloat16* dst;
  int k;
  if (i4 < nq)                { src = qkv_w;  dst = qkvb;  k = i4; }
  else if (i4 < nq + np)      { src = proj_w; dst = projb; k = i4 - nq; }
  else if (i4 < nq + np + n1) { src = fc1_w;  dst = fc1b;  k = i4 - nq - np; }
  else                        { src = fc2_w;  dst = fc2b;  k = i4 - nq - np - n1; }
  float4v v = *(const float4v*)(src + 4 * (size_t)k);
  #pragma unroll
  for (int l = 0; l < 4; ++l) dst[4 * (size_t)k + l] = __float2bfloat16(v[l]);
}

// ---------------- transpose NCHW fp32 -> token-major bf16 (raw + BN'd) ----------------

__global__ __launch_bounds__(256) void transpose_x(
    const float* __restrict__ x, __hip_bfloat16* __restrict__ xnt,
    __hip_bfloat16* __restrict__ xt, const float* __restrict__ cst) {
  __shared__ float tile[32][33];
  const int n0 = blockIdx.x * 32;
  const int c0 = blockIdx.y * 32;
  const int b  = blockIdx.z;
  const int j = threadIdx.x & 31, i = threadIdx.x >> 5;
  #pragma unroll
  for (int p = 0; p < 4; ++p) {
    int cc = c0 + i + p * 8;
    int n = n0 + j;
    if (n < NTOK) tile[i + p * 8][j] = x[((size_t)b * CCH + cc) * NTOK + n];
  }
  __syncthreads();
  const float s = cst[c0 + j], t = cst[512 + c0 + j];
  #pragma unroll
  for (int p = 0; p < 4; ++p) {
    int n = n0 + i + p * 8;
    int cc = c0 + j;
    if (n < NTOK) {
      float raw = tile[j][i + p * 8];
      size_t o = ((size_t)b * NTOK + n) * CCH + cc;
      xt[o]  = __float2bfloat16(raw);
      xnt[o] = __float2bfloat16(raw * s + t);
    }
  }
}

// ---------------- big-tile GEMM: C[M,N] = A[M,K]*B[N,K]^T, bf16 in, fp32 acc ----------------
// BM=256 fixed, BN in {256,128}; 512 threads = 8 waves.
// BN=256: wave grid 2Mx4N, per-wave 128x64.  BN=128: wave grid 4Mx2N, per-wave 64x64.
// 2-phase dbuf, BK=64, global_load_lds w/ pre-swizzled source, chunk-XOR LDS swizzle.
// EPI: 0 = plain bf16 (QKV)    1 = proj: x1t = xt + ls1*(v+bias)  (bf16 tm)
//      2 = fc1: gelu(v+bias)   3 = fc2: out = x1t + ls2*(v+bias) -> NCHW fp32 (LDS transpose)

template<int BN, int EPI>
__global__ __launch_bounds__(512, 2) void gemm256(
    const __hip_bfloat16* __restrict__ A, const __hip_bfloat16* __restrict__ Bw,
    int N, int K, int NY,
    __hip_bfloat16* __restrict__ outb, float* __restrict__ outf,
    const float* __restrict__ bias, const float* __restrict__ ls,
    const __hip_bfloat16* __restrict__ resid) {
  constexpr int LDSZ = (256 + BN) * 64 * 2 * 2;   // dbuf: A 32KB + B (BN/256*32)KB per buf
  constexpr int BUFSZ = LDSZ / 2;
  __shared__ char lds[LDSZ];
  const int tid  = threadIdx.x;
  const int lane = tid & 63;
  const int wave = tid >> 6;

  // bijective XCD swizzle (m204)
  const int nwg = (int)gridDim.x;
  const int q8 = nwg >> 3, r8 = nwg & 7;
  const int orig = blockIdx.x;
  const int xcd = orig & 7;
  const int wgid = (xcd < r8 ? xcd * (q8 + 1) : r8 * (q8 + 1) + (xcd - r8) * q8) + (orig >> 3);
  const int bx = wgid / NY;
  const int by = wgid - bx * NY;

  const int m0 = bx * 256;
  const int n0 = by * BN;
  constexpr int WRM = (BN == 256) ? 8 : 4;          // A-frags per wave
  const int wm = (BN == 256) ? (wave >> 2) * 128 : (wave >> 1) * 64;
  const int wn = (BN == 256) ? (wave & 3) * 64 : (wave & 1) * 64;
  const int KT = K >> 6;

  float4v acc[WRM][4] = {};

  auto stage = [&](int buf, int kt) {
    const int kb = kt * 64;
    char* base = lds + buf * BUFSZ;
    #pragma unroll
    for (int s = 0; s < 4; ++s) {                   // A: 32KB
      int L = s * 8192 + tid * 16;
      int row = L >> 7;
      int pc = (L >> 4) & 7;
      int c = pc ^ (row & 7);
      gload_lds16(A + (size_t)(m0 + row) * K + kb + c * 8, base + L);
    }
    #pragma unroll
    for (int s = 0; s < BN / 64; ++s) {             // B
      int L = s * 8192 + tid * 16;
      int row = L >> 7;
      int pc = (L >> 4) & 7;
      int c = pc ^ (row & 7);
      gload_lds16(Bw + (size_t)(n0 + row) * K + kb + c * 8, base + 32768 + L);
    }
  };

  auto compute = [&](int buf) {
    const char* bA = lds + buf * BUFSZ;
    const char* bB = bA + 32768;
    #pragma unroll
    for (int ks = 0; ks < 2; ++ks) {
      short8v av[WRM], bv[4];
      #pragma unroll
      for (int t = 0; t < WRM; ++t) {
        int row = wm + t * 16 + (lane & 15);
        int ph = (ks * 4 + (lane >> 4)) ^ (row & 7);
        av[t] = *(const short8v*)(bA + row * 128 + ph * 16);
      }
      #pragma unroll
      for (int j = 0; j < 4; ++j) {
        int row = wn + j * 16 + (lane & 15);
        int ph = (ks * 4 + (lane >> 4)) ^ (row & 7);
        bv[j] = *(const short8v*)(bB + row * 128 + ph * 16);
      }
      #pragma unroll
      for (int i = 0; i < WRM; ++i)
        #pragma unroll
        for (int j = 0; j < 4; ++j)
          mfma16x16(acc[i][j], av[i], bv[j]);
    }
  };

  stage(0, 0);
  __syncthreads();
  for (int kt = 0; kt < KT; ++kt) {
    if (kt + 1 < KT) stage((kt + 1) & 1, kt + 1);
    compute(kt & 1);
    __syncthreads();
  }
  asm volatile("s_nop 7\n\ts_nop 7");      // MFMA->VALU hazard guard

  if (EPI == 0 || EPI == 2) {
    #pragma unroll
    for (int i = 0; i < WRM; ++i)
      #pragma unroll
      for (int j = 0; j < 4; ++j)
        #pragma unroll
        for (int r = 0; r < 4; ++r) {
          int m = m0 + wm + i * 16 + ((lane >> 4) << 2) + r;
          int n = n0 + wn + j * 16 + (lane & 15);
          float v = acc[i][j][r];
          if (EPI == 0) {
            outb[(size_t)m * N + n] = __float2bfloat16(v);
          } else {
            float z = v + bias[n];
            float g = 0.5f * z * (1.0f + erff(z * 0.70710678118654752f));
            outb[(size_t)m * N + n] = __float2bfloat16(g);
          }
        }
  } else if (EPI == 1) {
    #pragma unroll
    for (int i = 0; i < WRM; ++i)
      #pragma unroll
      for (int j = 0; j < 4; ++j)
        #pragma unroll
        for (int r = 0; r < 4; ++r) {
          int m = m0 + wm + i * 16 + ((lane >> 4) << 2) + r;
          int n = n0 + wn + j * 16 + (lane & 15);
          float v = acc[i][j][r] + bias[n];
          v = __bfloat162float(resid[(size_t)m * CCH + n]) + ls[n] * v;
          outb[(size_t)m * CCH + n] = __float2bfloat16(v);
        }
  } else {   // EPI == 3 : epilogue + in-LDS transpose -> NCHW fp32 (BN==128)
    float* LT = (float*)lds;   // [64][260] fp32 = 66560 B
    #pragma unroll 1
    for (int h = 0; h < 2; ++h) {
      __syncthreads();
      if ((wave & 1) == h) {
        #pragma unroll
        for (int i = 0; i < WRM; ++i)
          #pragma unroll
          for (int j = 0; j < 4; ++j)
            #pragma unroll
            for (int r = 0; r < 4; ++r) {
              int ml = wm + i * 16 + ((lane >> 4) << 2) + r;   // 0..255 (wn folded out)
              int nl = j * 16 + (lane & 15);                    // 0..63
              int ng = n0 + h * 64 + nl;
              float v = acc[i][j][r] + bias[ng];
              v = __bfloat162float(resid[(size_t)(m0 + ml) * CCH + ng]) + ls[ng] * v;
              LT[nl * 260 + ml] = v;
            }
      }
      __syncthreads();
      #pragma unroll 1
      for (int w = 0; w < 8; ++w) {
        int nl = (tid >> 6) + w * 8;          // 0..63
        int ng = n0 + h * 64 + nl;
        int ml = (tid & 63) * 4;
        float4v v4 = *(const float4v*)(LT + nl * 260 + ml);
        int m = m0 + ml;
        int bb = m / NTOK, tt = m - bb * NTOK;
        if (tt <= NTOK - 4) {
          *(float4v*)(outf + (size_t)bb * (CCH * NTOK) + (size_t)ng * NTOK + tt) = v4;
        } else {
          #pragma unroll
          for (int e = 0; e < 4; ++e) {
            int m2 = m + e;
            int b2 = m2 / NTOK, t2 = m2 - b2 * NTOK;
            outf[(size_t)b2 * (CCH * NTOK) + (size_t)ng * NTOK + t2] = v4[e];
          }
        }
      }
    }
  }
}

// ---------------- attention: one block per (batch, head) ----------------

__global__ __launch_bounds__(256, 2) void attn_kernel(
    const __hip_bfloat16* __restrict__ qkv, __hip_bfloat16* __restrict__ o_t) {
  __shared__ char sQ[208 * 64];    // [208][32] bf16, chunk-swizzled rows
  __shared__ char sK[224 * 64];    // [224][32] bf16
  __shared__ char sV[32 * 448];    // V^T [32][224] bf16, chunk-swizzled
  __shared__ char sP[4][16 * 472]; // per-wave P [16][236] bf16
  const int tid  = threadIdx.x;
  const int lane = tid & 63;
  const int wave = tid >> 6;
  const int b = blockIdx.x >> 4;
  const int h = blockIdx.x & 15;
  const size_t qbase = (size_t)b * NTOK * 1536 + h * 32;

  {
    uint32_t* z = (uint32_t*)sQ;
    for (int i = tid; i < (208 * 64) / 4; i += 256) z[i] = 0u;
    z = (uint32_t*)sK;
    for (int i = tid; i < (224 * 64) / 4; i += 256) z[i] = 0u;
    z = (uint32_t*)sV;
    for (int i = tid; i < (32 * 448) / 4; i += 256) z[i] = 0u;
  }
  __syncthreads();

  for (int p = tid; p < NTOK * 4; p += 256) {
    int row = p >> 2, c = p & 3;
    const __hip_bfloat16* src = qkv + qbase + (size_t)row * 1536 + c * 8;
    short8v q = *(const short8v*)(src);
    short8v k = *(const short8v*)(src + 512);
    short8v v = *(const short8v*)(src + 1024);
    int pc = c ^ swz4(row);
    *(short8v*)(sQ + row * 64 + pc * 16) = q;
    *(short8v*)(sK + row * 64 + pc * 16) = k;
    #pragma unroll
    for (int j = 0; j < 8; ++j) {
      int d = c * 8 + j;
      int ch = (row >> 3) ^ swz4(d);
      *(uint16_t*)(sV + d * 448 + ch * 16 + (row & 7) * 2) = (uint16_t)v[j];
    }
  }
  __syncthreads();

  const float scale = 0.17677669529663687f;   // 1/sqrt(32)
  char* Pw = sP[wave];

  for (int mt = wave; mt < 13; mt += 4) {
    int qrow = mt * 16 + (lane & 15);
    int pcq = (lane >> 4) ^ swz4(qrow);
    short8v aq = *(const short8v*)(sQ + qrow * 64 + pcq * 16);

    float4v s[14];
    #pragma unroll
    for (int nt = 0; nt < 14; ++nt) {
      int krow = nt * 16 + (lane & 15);
      int pck = (lane >> 4) ^ swz4(krow);
      short8v bk = *(const short8v*)(sK + krow * 64 + pck * 16);
      s[nt] = float4v{0.f, 0.f, 0.f, 0.f};
      mfma16x16(s[nt], aq, bk);
    }
    asm volatile("s_nop 7\n\ts_nop 7");

    float mx[4] = {-INFINITY, -INFINITY, -INFINITY, -INFINITY};
    #pragma unroll
    for (int nt = 0; nt < 14; ++nt) {
      bool valid = (nt * 16 + (lane & 15)) < NTOK;
      #pragma unroll
      for (int r = 0; r < 4; ++r) {
        float v = valid ? s[nt][r] * scale : -INFINITY;
        s[nt][r] = v;
        mx[r] = fmaxf(mx[r], v);
      }
    }
    #pragma unroll
    for (int off = 1; off < 16; off <<= 1) {
      #pragma unroll
      for (int r = 0; r < 4; ++r) mx[r] = fmaxf(mx[r], __shfl_xor(mx[r], off));
    }
    float sum[4] = {0.f, 0.f, 0.f, 0.f};
    #pragma unroll
    for (int nt = 0; nt < 14; ++nt) {
      #pragma unroll
      for (int r = 0; r < 4; ++r) {
        float e = __expf(s[nt][r] - mx[r]);
        s[nt][r] = e;
        sum[r] += e;
      }
    }
    #pragma unroll
    for (int off = 1; off < 16; off <<= 1) {
      #pragma unroll
      for (int r = 0; r < 4; ++r) sum[r] += __shfl_xor(sum[r], off);
    }
    float rs[4];
    #pragma unroll
    for (int r = 0; r < 4; ++r) rs[r] = 1.0f / sum[r];

    #pragma unroll
    for (int nt = 0; nt < 14; ++nt) {
      int col = nt * 16 + (lane & 15);
      #pragma unroll
      for (int r = 0; r < 4; ++r) {
        int prow = ((lane >> 4) << 2) + r;
        *(__hip_bfloat16*)(Pw + prow * 472 + col * 2) = __float2bfloat16(s[nt][r] * rs[r]);
      }
    }

    float4v o0 = float4v{0.f, 0.f, 0.f, 0.f};
    float4v o1 = float4v{0.f, 0.f, 0.f, 0.f};
    #pragma unroll
    for (int ks = 0; ks < 7; ++ks) {
      short8v pa = *(const short8v*)(Pw + (lane & 15) * 472 + ks * 64 + ((lane >> 4) << 4));
      int kc = ks * 4 + (lane >> 4);
      int d0 = (lane & 15);
      int d1 = 16 + (lane & 15);
      short8v v0 = *(const short8v*)(sV + d0 * 448 + ((kc ^ swz4(d0)) << 4));
      short8v v1 = *(const short8v*)(sV + d1 * 448 + ((kc ^ swz4(d1)) << 4));
      mfma16x16(o0, pa, v0);
      mfma16x16(o1, pa, v1);
    }
    asm volatile("s_nop 7\n\ts_nop 7");

    #pragma unroll
    for (int r = 0; r < 4; ++r) {
      int trow = mt * 16 + ((lane >> 4) << 2) + r;
      if (trow < NTOK) {
        size_t ob = ((size_t)b * NTOK + trow) * CCH + h * 32 + (lane & 15);
        o_t[ob] = __float2bfloat16(o0[r]);
        o_t[ob + 16] = __float2bfloat16(o1[r]);
      }
    }
  }
}

// ---------------- depthwise 7x7 conv, token-major (+BN in, +fBN out) ----------------

__global__ __launch_bounds__(448) void dwconv_tm(
    const __hip_bfloat16* __restrict__ x1t, const float* __restrict__ dw_w,
    const float* __restrict__ cst, __hip_bfloat16* __restrict__ yt) {
  __shared__ float img[196][32];
  __shared__ float wgt[49][32];
  const int tid = threadIdx.x;
  const int b  = blockIdx.x >> 4;
  const int cb = (blockIdx.x & 15) * 32;
  const int c  = tid & 31;
  const int gc = cb + c;
  const float s = cst[gc], t0 = cst[512 + gc];
  #pragma unroll
  for (int k = 0; k < 14; ++k) {
    int p = (tid >> 5) + k * 14;
    img[p][c] = __bfloat162float(x1t[((size_t)b * NTOK + p) * CCH + gc]) * s + t0;
  }
  for (int i = tid; i < 49 * 32; i += 448) {
    int tap = i >> 5, cc = i & 31;
    wgt[tap][cc] = dw_w[(cb + cc) * 49 + tap];
  }
  __syncthreads();

  const int px = tid >> 5;        // 0..13
  float out[14];
  #pragma unroll
  for (int i = 0; i < 14; ++i) out[i] = 0.f;
  #pragma unroll 1
  for (int row = 0; row < 14; ++row) {
    float v[7];
    #pragma unroll
    for (int dx = 0; dx < 7; ++dx) {
      int ix = px + dx - 3;
      v[dx] = ((unsigned)ix < 14u) ? img[row * 14 + ix][c] : 0.f;
    }
    #pragma unroll
    for (int kk = 0; kk < 7; ++kk) {
      int py = row + 3 - kk;
      if (py >= 0 && py < 14) {
        float hsum = 0.f;
        #pragma unroll
        for (int dx = 0; dx < 7; ++dx) hsum = fmaf(v[dx], wgt[kk * 7 + dx][c], hsum);
        out[py] += hsum;
      }
    }
  }
  const float fs = cst[1024 + gc], ft = cst[1536 + gc];
  #pragma unroll
  for (int py = 0; py < 14; ++py)
    yt[((size_t)b * NTOK + py * 14 + px) * CCH + gc] = __float2bfloat16(out[py] * fs + ft);
}

// ---------------- launch ----------------

extern "C" void kernel_launch(void* const* d_in, const int* in_sizes, int n_in,
                              void* d_out, int out_size, void* d_ws, size_t ws_size,
                              hipStream_t stream) {
  const float* x      = (const float*)d_in[0];
  const float* bn_g   = (const float*)d_in[1];
  const float* bn_b   = (const float*)d_in[2];
  const float* bn_m   = (const float*)d_in[3];
  const float* bn_v   = (const float*)d_in[4];
  const float* qkv_w  = (const float*)d_in[5];
  const float* proj_w = (const float*)d_in[6];
  const float* proj_b = (const float*)d_in[7];
  const float* dw_w   = (const float*)d_in[8];
  const float* fbn_g  = (const float*)d_in[9];
  const float* fbn_b  = (const float*)d_in[10];
  const float* fbn_m  = (const float*)d_in[11];
  const float* fbn_v  = (const float*)d_in[12];
  const float* fc1_w  = (const float*)d_in[13];
  const float* fc1_b  = (const float*)d_in[14];
  const float* fc2_w  = (const float*)d_in[15];
  const float* fc2_b  = (const float*)d_in[16];
  const float* ls1    = (const float*)d_in[17];
  const float* ls2    = (const float*)d_in[18];

  char* ws = (char*)d_ws;
  float* cst             = (float*)ws;                       // 8 KB
  __hip_bfloat16* qkvb   = (__hip_bfloat16*)(ws + 8192);
  __hip_bfloat16* projb  = (__hip_bfloat16*)(ws + 1581056);
  __hip_bfloat16* fc1b   = (__hip_bfloat16*)(ws + 2105344);
  __hip_bfloat16* fc2b   = (__hip_bfloat16*)(ws + 4202496);
  __hip_bfloat16* xnt    = (__hip_bfloat16*)(ws + 6299648);   // 12.85 MB
  __hip_bfloat16* xt     = (__hip_bfloat16*)(ws + 19144704);  // 12.85 MB
  __hip_bfloat16* qkvt   = (__hip_bfloat16*)(ws + 31989760);  // 38.5 MB
  __hip_bfloat16* ot     = (__hip_bfloat16*)(ws + 70524928);  // 12.85 MB
  __hip_bfloat16* x1t    = (__hip_bfloat16*)(ws + 83369984);  // 12.85 MB
  __hip_bfloat16* yt     = (__hip_bfloat16*)(ws + 96215040);  // 12.85 MB (end 109060096)
  __hip_bfloat16* hbuf   = (__hip_bfloat16*)(ws + 6299648);   // 51.4 MB overlay (xnt/xt/qkvt dead)

  prep_consts<<<dim3(2), dim3(256), 0, stream>>>(bn_g, bn_b, bn_m, bn_v,
                                                 fbn_g, fbn_b, fbn_m, fbn_v, cst);
  cvt_weights<<<dim3(3072), dim3(256), 0, stream>>>(qkv_w, proj_w, fc1_w, fc2_w,
                                                    qkvb, projb, fc1b, fc2b);
  transpose_x<<<dim3(7, 16, 64), dim3(256), 0, stream>>>(x, xnt, xt, cst);
  // QKV: M=12544, N=1536, K=512 ; 256x256 tiles -> 49*6 = 294 blocks
  gemm256<256, 0><<<dim3(294), dim3(512), 0, stream>>>(xnt, qkvb, 1536, 512, 6,
                                                       qkvt, nullptr, nullptr, nullptr, nullptr);
  attn_kernel<<<dim3(1024), dim3(256), 0, stream>>>(qkvt, ot);
  // proj: N=512, K=512 ; 256x128 tiles -> 49*4 = 196 blocks
  gemm256<128, 1><<<dim3(196), dim3(512), 0, stream>>>(ot, projb, 512, 512, 4,
                                                       x1t, nullptr, proj_b, ls1, xt);
  dwconv_tm<<<dim3(1024), dim3(448), 0, stream>>>(x1t, dw_w, cst, yt);
  // fc1: N=2048, K=512 ; 256x256 tiles -> 49*8 = 392 blocks
  gemm256<256, 2><<<dim3(392), dim3(512), 0, stream>>>(yt, fc1b, 2048, 512, 8,
                                                       hbuf, nullptr, fc1_b, nullptr, nullptr);
  // fc2: N=512, K=2048 ; 256x128 tiles -> 49*4 = 196 blocks ; NCHW fp32 out
  gemm256<128, 3><<<dim3(196), dim3(512), 0, stream>>>(hbuf, fc2b, 512, 2048, 4,
                                                       nullptr, (float*)d_out, fc2_b, ls2, x1t);
}

// Round 4
// 241.405 us; speedup vs baseline: 1.0649x; 1.0649x over previous
//
#include <hip/hip_runtime.h>
#include <hip/hip_bf16.h>
#include <stdint.h>

#define NTOK 196
#define NB   64
#define CCH  512
#define HID  2048
#define MTOT (NB * NTOK)   // 12544

typedef __attribute__((ext_vector_type(8))) short  short8v;
typedef __attribute__((ext_vector_type(4))) float  float4v;

// ---------------- helpers ----------------

__device__ __forceinline__ void mfma16x16(float4v& d, short8v a, short8v b) {
  asm("v_mfma_f32_16x16x32_bf16 %0, %1, %2, %0" : "+v"(d) : "v"(a), "v"(b));
}

__device__ __forceinline__ void gload_lds16(const void* gsrc, void* ldst) {
  __builtin_amdgcn_global_load_lds(
      (const __attribute__((address_space(1))) unsigned int*)gsrc,
      (__attribute__((address_space(3))) unsigned int*)ldst, 16, 0, 0);
}

__device__ __forceinline__ int swz4(int r) { return (r ^ (r >> 2)) & 3; }

// ---------------- prep: BN constants ----------------

__global__ void prep_consts(const float* __restrict__ bn_g, const float* __restrict__ bn_b,
                            const float* __restrict__ bn_m, const float* __restrict__ bn_v,
                            const float* __restrict__ fbn_g, const float* __restrict__ fbn_b,
                            const float* __restrict__ fbn_m, const float* __restrict__ fbn_v,
                            float* __restrict__ cst) {
  int c = blockIdx.x * blockDim.x + threadIdx.x;
  if (c < CCH) {
    float i1 = bn_g[c] * rsqrtf(bn_v[c] + 1e-5f);
    cst[c] = i1;
    cst[512 + c] = bn_b[c] - bn_m[c] * i1;
    float i2 = fbn_g[c] * rsqrtf(fbn_v[c] + 1e-5f);
    cst[1024 + c] = i2;
    cst[1536 + c] = fbn_b[c] - fbn_m[c] * i2;
  }
}

// ---------------- weights fp32 -> bf16 ----------------

__global__ void cvt_weights(const float* __restrict__ qkv_w, const float* __restrict__ proj_w,
                            const float* __restrict__ fc1_w, const float* __restrict__ fc2_w,
                            __hip_bfloat16* __restrict__ qkvb, __hip_bfloat16* __restrict__ projb,
                            __hip_bfloat16* __restrict__ fc1b, __hip_bfloat16* __restrict__ fc2b) {
  int i4 = blockIdx.x * blockDim.x + threadIdx.x;    // unit = 4 floats
  const int nq = 1536 * 512 / 4;
  const int np = 512 * 512 / 4;
  const int n1 = 2048 * 512 / 4;
  const float* src;
  __hip_bfloat16* dst;
  int k;
  if (i4 < nq)                { src = qkv_w;  dst = qkvb;  k = i4; }
  else if (i4 < nq + np)      { src = proj_w; dst = projb; k = i4 - nq; }
  else if (i4 < nq + np + n1) { src = fc1_w;  dst = fc1b;  k = i4 - nq - np; }
  else                        { src = fc2_w;  dst = fc2b;  k = i4 - nq - np - n1; }
  float4v v = *(const float4v*)(src + 4 * (size_t)k);
  #pragma unroll
  for (int l = 0; l < 4; ++l) dst[4 * (size_t)k + l] = __float2bfloat16(v[l]);
}

// ---------------- transpose NCHW fp32 -> token-major bf16 (raw + BN'd) ----------------

__global__ __launch_bounds__(256) void transpose_x(
    const float* __restrict__ x, __hip_bfloat16* __restrict__ xnt,
    __hip_bfloat16* __restrict__ xt, const float* __restrict__ cst) {
  __shared__ float tile[32][33];
  const int n0 = blockIdx.x * 32;
  const int c0 = blockIdx.y * 32;
  const int b  = blockIdx.z;
  const int j = threadIdx.x & 31, i = threadIdx.x >> 5;
  #pragma unroll
  for (int p = 0; p < 4; ++p) {
    int cc = c0 + i + p * 8;
    int n = n0 + j;
    if (n < NTOK) tile[i + p * 8][j] = x[((size_t)b * CCH + cc) * NTOK + n];
  }
  __syncthreads();
  const float s = cst[c0 + j], t = cst[512 + c0 + j];
  #pragma unroll
  for (int p = 0; p < 4; ++p) {
    int n = n0 + i + p * 8;
    int cc = c0 + j;
    if (n < NTOK) {
      float raw = tile[j][i + p * 8];
      size_t o = ((size_t)b * NTOK + n) * CCH + cc;
      xt[o]  = __float2bfloat16(raw);
      xnt[o] = __float2bfloat16(raw * s + t);
    }
  }
}

// ---------------- pipelined GEMM: C[M,N] = A[M,K]*B[N,K]^T, bf16, fp32 acc ----------------
// BM=256, BN in {256,128}; 512 threads = 8 waves; BK=32.
// Ring of 4 LDS slots (32KB each: 256 rows x 128B, A|B interleaved + XOR swizzle),
// prefetch distance 2, counted s_waitcnt vmcnt(4) (never drains in main loop),
// one raw s_barrier per K-tile, setprio around MFMA cluster.
// EPI: 0 = plain bf16 (QKV)    1 = proj: x1t = xt + ls1*(v+bias)  (bf16 tm)
//      2 = fc1: gelu(v+bias)   3 = fc2: out = x1t + ls2*(v+bias) -> NCHW fp32 (LDS transpose)

template<int BN, int EPI>
__global__ __launch_bounds__(512, 2) void gemmP(
    const __hip_bfloat16* __restrict__ A, const __hip_bfloat16* __restrict__ Bw,
    int N, int K, int NY,
    __hip_bfloat16* __restrict__ outb, float* __restrict__ outf,
    const float* __restrict__ bias, const float* __restrict__ ls,
    const __hip_bfloat16* __restrict__ resid) {
  __shared__ char lds[131072];   // 4 ring slots x 32KB
  const int tid  = threadIdx.x;
  const int lane = tid & 63;
  const int wave = tid >> 6;

  // bijective XCD swizzle (m204)
  const int nwg = (int)gridDim.x;
  const int q8 = nwg >> 3, r8 = nwg & 7;
  const int orig = blockIdx.x;
  const int xcd = orig & 7;
  const int wgid = (xcd < r8 ? xcd * (q8 + 1) : r8 * (q8 + 1) + (xcd - r8) * q8) + (orig >> 3);
  const int bx = wgid / NY;
  const int by = wgid - bx * NY;

  const int m0 = bx * 256;
  const int n0 = by * BN;
  constexpr int WRM = (BN == 256) ? 8 : 4;          // A-frags per wave
  const int wm = (BN == 256) ? (wave >> 2) * 128 : (wave >> 1) * 64;
  const int wn = (BN == 256) ? (wave & 3) * 64 : (wave & 1) * 64;
  const int KT = K >> 5;

  float4v acc[WRM][4] = {};

  // stage tile kt into ring slot kt&3 (4 x 8KB rounds; src chunk pre-swizzled)
  auto stage = [&](int kt) {
    char* base = lds + (kt & 3) * 32768;
    const int kb = kt * 32;
    #pragma unroll
    for (int s = 0; s < 4; ++s) {
      int L = s * 8192 + tid * 16;
      int r  = L >> 7;              // LDS row (0..255)
      int ph = (L >> 6) & 1;        // physical half within 128B row
      int pc = (L >> 4) & 3;        // physical 16B chunk within half
      int lh = ph ^ ((r >> 2) & 1); // logical operand: 0=A, 1=B
      int lc = pc ^ (r & 3);        // logical k-chunk (0..3)
      const __hip_bfloat16* src = lh
          ? Bw + (size_t)(n0 + (r & (BN - 1))) * K + kb + lc * 8
          : A  + (size_t)(m0 + r) * K + kb + lc * 8;
      gload_lds16(src, base + L);
    }
  };

  auto compute = [&](int kt) {
    const char* base = lds + (kt & 3) * 32768;
    const int c = lane >> 4;                 // k-chunk 0..3 (8 bf16 each)
    short8v bv[4];
    #pragma unroll
    for (int j = 0; j < 4; ++j) {
      int r = wn + j * 16 + (lane & 15);
      int pc8 = ((1 ^ ((r >> 2) & 1)) << 2) + (c ^ (r & 3));
      bv[j] = *(const short8v*)(base + r * 128 + pc8 * 16);
    }
    short8v av[WRM];
    #pragma unroll
    for (int t = 0; t < WRM; ++t) {
      int r = wm + t * 16 + (lane & 15);
      int pc8 = (((r >> 2) & 1) << 2) + (c ^ (r & 3));
      av[t] = *(const short8v*)(base + r * 128 + pc8 * 16);
    }
    __builtin_amdgcn_s_setprio(1);
    #pragma unroll
    for (int i = 0; i < WRM; ++i)
      #pragma unroll
      for (int j = 0; j < 4; ++j)
        mfma16x16(acc[i][j], av[i], bv[j]);
    __builtin_amdgcn_s_setprio(0);
  };

  stage(0);
  stage(1);
  for (int kt = 0; kt < KT; ++kt) {
    if (kt + 1 < KT) asm volatile("s_waitcnt vmcnt(4)" ::: "memory");
    else             asm volatile("s_waitcnt vmcnt(0)" ::: "memory");
    __builtin_amdgcn_s_barrier();
    __builtin_amdgcn_sched_barrier(0);
    if (kt + 2 < KT) stage(kt + 2);
    __builtin_amdgcn_sched_barrier(0);
    compute(kt);
  }
  asm volatile("s_nop 7\n\ts_nop 7");      // MFMA->VALU hazard guard

  if (EPI == 0 || EPI == 2) {
    #pragma unroll
    for (int i = 0; i < WRM; ++i)
      #pragma unroll
      for (int j = 0; j < 4; ++j)
        #pragma unroll
        for (int r = 0; r < 4; ++r) {
          int m = m0 + wm + i * 16 + ((lane >> 4) << 2) + r;
          int n = n0 + wn + j * 16 + (lane & 15);
          float v = acc[i][j][r];
          if (EPI == 0) {
            outb[(size_t)m * N + n] = __float2bfloat16(v);
          } else {
            float z = v + bias[n];
            float g = z / (1.0f + __expf(-1.702f * z));   // fast GELU (err ~2e-2, x1e-5 after ls2)
            outb[(size_t)m * N + n] = __float2bfloat16(g);
          }
        }
  } else if (EPI == 1) {
    #pragma unroll
    for (int i = 0; i < WRM; ++i)
      #pragma unroll
      for (int j = 0; j < 4; ++j)
        #pragma unroll
        for (int r = 0; r < 4; ++r) {
          int m = m0 + wm + i * 16 + ((lane >> 4) << 2) + r;
          int n = n0 + wn + j * 16 + (lane & 15);
          float v = acc[i][j][r] + bias[n];
          v = __bfloat162float(resid[(size_t)m * CCH + n]) + ls[n] * v;
          outb[(size_t)m * CCH + n] = __float2bfloat16(v);
        }
  } else {   // EPI == 3 : epilogue + in-LDS transpose -> NCHW fp32 (BN==128)
    float* LT = (float*)lds;   // [64][260] fp32 = 66560 B
    #pragma unroll 1
    for (int h = 0; h < 2; ++h) {
      __syncthreads();
      if ((wave & 1) == h) {
        #pragma unroll
        for (int i = 0; i < WRM; ++i)
          #pragma unroll
          for (int j = 0; j < 4; ++j)
            #pragma unroll
            for (int r = 0; r < 4; ++r) {
              int ml = wm + i * 16 + ((lane >> 4) << 2) + r;   // 0..255
              int nl = j * 16 + (lane & 15);                    // 0..63
              int ng = n0 + h * 64 + nl;
              float v = acc[i][j][r] + bias[ng];
              v = __bfloat162float(resid[(size_t)(m0 + ml) * CCH + ng]) + ls[ng] * v;
              LT[nl * 260 + ml] = v;
            }
      }
      __syncthreads();
      #pragma unroll 1
      for (int w = 0; w < 8; ++w) {
        int nl = (tid >> 6) + w * 8;          // 0..63
        int ng = n0 + h * 64 + nl;
        int ml = (tid & 63) * 4;
        float4v v4 = *(const float4v*)(LT + nl * 260 + ml);
        int m = m0 + ml;
        int bb = m / NTOK, tt = m - bb * NTOK;
        if (tt <= NTOK - 4) {
          *(float4v*)(outf + (size_t)bb * (CCH * NTOK) + (size_t)ng * NTOK + tt) = v4;
        } else {
          #pragma unroll
          for (int e = 0; e < 4; ++e) {
            int m2 = m + e;
            int b2 = m2 / NTOK, t2 = m2 - b2 * NTOK;
            outf[(size_t)b2 * (CCH * NTOK) + (size_t)ng * NTOK + t2] = v4[e];
          }
        }
      }
    }
  }
}

// ---------------- attention: one block per (batch, head) ----------------

__global__ __launch_bounds__(256, 2) void attn_kernel(
    const __hip_bfloat16* __restrict__ qkv, __hip_bfloat16* __restrict__ o_t) {
  __shared__ char sQ[208 * 64];    // [208][32] bf16, chunk-swizzled rows
  __shared__ char sK[224 * 64];    // [224][32] bf16
  __shared__ char sV[32 * 448];    // V^T [32][224] bf16, chunk-swizzled
  __shared__ char sP[4][16 * 472]; // per-wave P [16][236] bf16
  const int tid  = threadIdx.x;
  const int lane = tid & 63;
  const int wave = tid >> 6;
  const int b = blockIdx.x >> 4;
  const int h = blockIdx.x & 15;
  const size_t qbase = (size_t)b * NTOK * 1536 + h * 32;

  {
    uint32_t* z = (uint32_t*)sQ;
    for (int i = tid; i < (208 * 64) / 4; i += 256) z[i] = 0u;
    z = (uint32_t*)sK;
    for (int i = tid; i < (224 * 64) / 4; i += 256) z[i] = 0u;
    z = (uint32_t*)sV;
    for (int i = tid; i < (32 * 448) / 4; i += 256) z[i] = 0u;
  }
  __syncthreads();

  for (int p = tid; p < NTOK * 4; p += 256) {
    int row = p >> 2, c = p & 3;
    const __hip_bfloat16* src = qkv + qbase + (size_t)row * 1536 + c * 8;
    short8v q = *(const short8v*)(src);
    short8v k = *(const short8v*)(src + 512);
    short8v v = *(const short8v*)(src + 1024);
    int pc = c ^ swz4(row);
    *(short8v*)(sQ + row * 64 + pc * 16) = q;
    *(short8v*)(sK + row * 64 + pc * 16) = k;
    #pragma unroll
    for (int j = 0; j < 8; ++j) {
      int d = c * 8 + j;
      int ch = (row >> 3) ^ swz4(d);
      *(uint16_t*)(sV + d * 448 + ch * 16 + (row & 7) * 2) = (uint16_t)v[j];
    }
  }
  __syncthreads();

  const float scale = 0.17677669529663687f;   // 1/sqrt(32)
  char* Pw = sP[wave];

  for (int mt = wave; mt < 13; mt += 4) {
    int qrow = mt * 16 + (lane & 15);
    int pcq = (lane >> 4) ^ swz4(qrow);
    short8v aq = *(const short8v*)(sQ + qrow * 64 + pcq * 16);

    float4v s[14];
    #pragma unroll
    for (int nt = 0; nt < 14; ++nt) {
      int krow = nt * 16 + (lane & 15);
      int pck = (lane >> 4) ^ swz4(krow);
      short8v bk = *(const short8v*)(sK + krow * 64 + pck * 16);
      s[nt] = float4v{0.f, 0.f, 0.f, 0.f};
      mfma16x16(s[nt], aq, bk);
    }
    asm volatile("s_nop 7\n\ts_nop 7");

    float mx[4] = {-INFINITY, -INFINITY, -INFINITY, -INFINITY};
    #pragma unroll
    for (int nt = 0; nt < 14; ++nt) {
      bool valid = (nt * 16 + (lane & 15)) < NTOK;
      #pragma unroll
      for (int r = 0; r < 4; ++r) {
        float v = valid ? s[nt][r] * scale : -INFINITY;
        s[nt][r] = v;
        mx[r] = fmaxf(mx[r], v);
      }
    }
    #pragma unroll
    for (int off = 1; off < 16; off <<= 1) {
      #pragma unroll
      for (int r = 0; r < 4; ++r) mx[r] = fmaxf(mx[r], __shfl_xor(mx[r], off));
    }
    float sum[4] = {0.f, 0.f, 0.f, 0.f};
    #pragma unroll
    for (int nt = 0; nt < 14; ++nt) {
      #pragma unroll
      for (int r = 0; r < 4; ++r) {
        float e = __expf(s[nt][r] - mx[r]);
        s[nt][r] = e;
        sum[r] += e;
      }
    }
    #pragma unroll
    for (int off = 1; off < 16; off <<= 1) {
      #pragma unroll
      for (int r = 0; r < 4; ++r) sum[r] += __shfl_xor(sum[r], off);
    }
    float rs[4];
    #pragma unroll
    for (int r = 0; r < 4; ++r) rs[r] = 1.0f / sum[r];

    #pragma unroll
    for (int nt = 0; nt < 14; ++nt) {
      int col = nt * 16 + (lane & 15);
      #pragma unroll
      for (int r = 0; r < 4; ++r) {
        int prow = ((lane >> 4) << 2) + r;
        *(__hip_bfloat16*)(Pw + prow * 472 + col * 2) = __float2bfloat16(s[nt][r] * rs[r]);
      }
    }

    float4v o0 = float4v{0.f, 0.f, 0.f, 0.f};
    float4v o1 = float4v{0.f, 0.f, 0.f, 0.f};
    #pragma unroll
    for (int ks = 0; ks < 7; ++ks) {
      short8v pa = *(const short8v*)(Pw + (lane & 15) * 472 + ks * 64 + ((lane >> 4) << 4));
      int kc = ks * 4 + (lane >> 4);
      int d0 = (lane & 15);
      int d1 = 16 + (lane & 15);
      short8v v0 = *(const short8v*)(sV + d0 * 448 + ((kc ^ swz4(d0)) << 4));
      short8v v1 = *(const short8v*)(sV + d1 * 448 + ((kc ^ swz4(d1)) << 4));
      mfma16x16(o0, pa, v0);
      mfma16x16(o1, pa, v1);
    }
    asm volatile("s_nop 7\n\ts_nop 7");

    #pragma unroll
    for (int r = 0; r < 4; ++r) {
      int trow = mt * 16 + ((lane >> 4) << 2) + r;
      if (trow < NTOK) {
        size_t ob = ((size_t)b * NTOK + trow) * CCH + h * 32 + (lane & 15);
        o_t[ob] = __float2bfloat16(o0[r]);
        o_t[ob + 16] = __float2bfloat16(o1[r]);
      }
    }
  }
}

// ---------------- depthwise 7x7 conv, token-major (+BN in, +fBN out) ----------------

__global__ __launch_bounds__(448) void dwconv_tm(
    const __hip_bfloat16* __restrict__ x1t, const float* __restrict__ dw_w,
    const float* __restrict__ cst, __hip_bfloat16* __restrict__ yt) {
  __shared__ float img[196][32];
  __shared__ float wgt[49][32];
  const int tid = threadIdx.x;
  const int b  = blockIdx.x >> 4;
  const int cb = (blockIdx.x & 15) * 32;
  const int c  = tid & 31;
  const int gc = cb + c;
  const float s = cst[gc], t0 = cst[512 + gc];
  #pragma unroll
  for (int k = 0; k < 14; ++k) {
    int p = (tid >> 5) + k * 14;
    img[p][c] = __bfloat162float(x1t[((size_t)b * NTOK + p) * CCH + gc]) * s + t0;
  }
  for (int i = tid; i < 49 * 32; i += 448) {
    int tap = i >> 5, cc = i & 31;
    wgt[tap][cc] = dw_w[(cb + cc) * 49 + tap];
  }
  __syncthreads();

  const int px = tid >> 5;        // 0..13
  float out[14];
  #pragma unroll
  for (int i = 0; i < 14; ++i) out[i] = 0.f;
  #pragma unroll 1
  for (int row = 0; row < 14; ++row) {
    float v[7];
    #pragma unroll
    for (int dx = 0; dx < 7; ++dx) {
      int ix = px + dx - 3;
      v[dx] = ((unsigned)ix < 14u) ? img[row * 14 + ix][c] : 0.f;
    }
    #pragma unroll
    for (int kk = 0; kk < 7; ++kk) {
      int py = row + 3 - kk;
      if (py >= 0 && py < 14) {
        float hsum = 0.f;
        #pragma unroll
        for (int dx = 0; dx < 7; ++dx) hsum = fmaf(v[dx], wgt[kk * 7 + dx][c], hsum);
        out[py] += hsum;
      }
    }
  }
  const float fs = cst[1024 + gc], ft = cst[1536 + gc];
  #pragma unroll
  for (int py = 0; py < 14; ++py)
    yt[((size_t)b * NTOK + py * 14 + px) * CCH + gc] = __float2bfloat16(out[py] * fs + ft);
}

// ---------------- launch ----------------

extern "C" void kernel_launch(void* const* d_in, const int* in_sizes, int n_in,
                              void* d_out, int out_size, void* d_ws, size_t ws_size,
                              hipStream_t stream) {
  const float* x      = (const float*)d_in[0];
  const float* bn_g   = (const float*)d_in[1];
  const float* bn_b   = (const float*)d_in[2];
  const float* bn_m   = (const float*)d_in[3];
  const float* bn_v   = (const float*)d_in[4];
  const float* qkv_w  = (const float*)d_in[5];
  const float* proj_w = (const float*)d_in[6];
  const float* proj_b = (const float*)d_in[7];
  const float* dw_w   = (const float*)d_in[8];
  const float* fbn_g  = (const float*)d_in[9];
  const float* fbn_b  = (const float*)d_in[10];
  const float* fbn_m  = (const float*)d_in[11];
  const float* fbn_v  = (const float*)d_in[12];
  const float* fc1_w  = (const float*)d_in[13];
  const float* fc1_b  = (const float*)d_in[14];
  const float* fc2_w  = (const float*)d_in[15];
  const float* fc2_b  = (const float*)d_in[16];
  const float* ls1    = (const float*)d_in[17];
  const float* ls2    = (const float*)d_in[18];

  char* ws = (char*)d_ws;
  float* cst             = (float*)ws;                       // 8 KB
  __hip_bfloat16* qkvb   = (__hip_bfloat16*)(ws + 8192);
  __hip_bfloat16* projb  = (__hip_bfloat16*)(ws + 1581056);
  __hip_bfloat16* fc1b   = (__hip_bfloat16*)(ws + 2105344);
  __hip_bfloat16* fc2b   = (__hip_bfloat16*)(ws + 4202496);
  __hip_bfloat16* xnt    = (__hip_bfloat16*)(ws + 6299648);   // 12.85 MB
  __hip_bfloat16* xt     = (__hip_bfloat16*)(ws + 19144704);  // 12.85 MB
  __hip_bfloat16* qkvt   = (__hip_bfloat16*)(ws + 31989760);  // 38.5 MB
  __hip_bfloat16* ot     = (__hip_bfloat16*)(ws + 70524928);  // 12.85 MB
  __hip_bfloat16* x1t    = (__hip_bfloat16*)(ws + 83369984);  // 12.85 MB
  __hip_bfloat16* yt     = (__hip_bfloat16*)(ws + 96215040);  // 12.85 MB (end 109060096)
  __hip_bfloat16* hbuf   = (__hip_bfloat16*)(ws + 6299648);   // 51.4 MB overlay (xnt/xt/qkvt dead)

  prep_consts<<<dim3(2), dim3(256), 0, stream>>>(bn_g, bn_b, bn_m, bn_v,
                                                 fbn_g, fbn_b, fbn_m, fbn_v, cst);
  cvt_weights<<<dim3(3072), dim3(256), 0, stream>>>(qkv_w, proj_w, fc1_w, fc2_w,
                                                    qkvb, projb, fc1b, fc2b);
  transpose_x<<<dim3(7, 16, 64), dim3(256), 0, stream>>>(x, xnt, xt, cst);
  // QKV: M=12544, N=1536, K=512 ; 256x256 -> 49*6 = 294 blocks
  gemmP<256, 0><<<dim3(294), dim3(512), 0, stream>>>(xnt, qkvb, 1536, 512, 6,
                                                     qkvt, nullptr, nullptr, nullptr, nullptr);
  attn_kernel<<<dim3(1024), dim3(256), 0, stream>>>(qkvt, ot);
  // proj: N=512, K=512 ; 256x128 -> 49*4 = 196 blocks
  gemmP<128, 1><<<dim3(196), dim3(512), 0, stream>>>(ot, projb, 512, 512, 4,
                                                     x1t, nullptr, proj_b, ls1, xt);
  dwconv_tm<<<dim3(1024), dim3(448), 0, stream>>>(x1t, dw_w, cst, yt);
  // fc1: N=2048, K=512 ; 256x256 -> 49*8 = 392 blocks
  gemmP<256, 2><<<dim3(392), dim3(512), 0, stream>>>(yt, fc1b, 2048, 512, 8,
                                                     hbuf, nullptr, fc1_b, nullptr, nullptr);
  // fc2: N=512, K=2048 ; 256x128 -> 49*4 = 196 blocks ; NCHW fp32 out
  gemmP<128, 3><<<dim3(196), dim3(512), 0, stream>>>(hbuf, fc2b, 512, 2048, 4,
                                                     nullptr, (float*)d_out, fc2_b, ls2, x1t);
}